// Round 5
// baseline (466.464 us; speedup 1.0000x reference)
//
#include <hip/hip_runtime.h>
#include <math.h>

typedef __bf16 bf16;
typedef __bf16 bf16x8 __attribute__((ext_vector_type(8)));
typedef float f32x4 __attribute__((ext_vector_type(4)));
typedef unsigned short u16;
typedef unsigned int u32;

constexpr int BATCH = 32;
constexpr int CH    = 512;   // C
constexpr int CI    = 256;   // C/2
constexpr int NSP   = 1024;  // H*W
constexpr int OCH   = 768;   // 3*CI (theta|phi|g concat)
constexpr float EPSV = 1e-5f;

// ---------------------------------------------------------------------------
// K0a: weights -> bf16, k-blocked tiles of 64.
// ---------------------------------------------------------------------------
__global__ void prep_weights(const float* __restrict__ Wg, const float* __restrict__ Wt,
                             const float* __restrict__ Wp, const float* __restrict__ Wz,
                             bf16* __restrict__ wc, bf16* __restrict__ wz) {
    int tid = blockIdx.x * 256 + threadIdx.x;
    if (tid < OCH * CH) {
        int r = tid / CH, c = tid % CH;
        float v;
        if (r < 256)      v = Wt[r * CH + c];
        else if (r < 512) v = Wp[(r - 256) * CH + c];
        else              v = Wg[(r - 512) * CH + c];
        wc[(size_t)(c >> 6) * (OCH * 64) + r * 64 + (c & 63)] = (bf16)v;
    } else {
        int t2 = tid - OCH * CH;
        if (t2 < CH * CI) {
            int r = t2 / CI, o = t2 % CI;
            wz[(size_t)(o >> 6) * (CH * 64) + r * 64 + (o & 63)] = (bf16)Wz[r * CI + o];
        }
    }
}

__global__ void zero_sums(float* __restrict__ sums) {
    int t = threadIdx.x;
    #pragma unroll
    for (int i = 0; i < 4; ++i) sums[t + i * 256] = 0.0f;
}

// ---------------------------------------------------------------------------
// K0b: x [b][c][n] fp32 -> xb [b][kt][n][64] bf16 (64x64 LDS transpose tiles)
// ---------------------------------------------------------------------------
__global__ void transpose_x(const float* __restrict__ x, bf16* __restrict__ xb) {
    __shared__ bf16 tile[64][64];
    int b = blockIdx.z, kt = blockIdx.y, nb = blockIdx.x;
    int t = threadIdx.x;
    {
        int c_loc = t >> 2;
        int nq = t & 3;
        const float* src = x + ((size_t)b * CH + kt * 64 + c_loc) * NSP + nb * 64 + nq * 16;
        float vv[16];
        *(float4*)(vv + 0)  = *(const float4*)(src + 0);
        *(float4*)(vv + 4)  = *(const float4*)(src + 4);
        *(float4*)(vv + 8)  = *(const float4*)(src + 8);
        *(float4*)(vv + 12) = *(const float4*)(src + 12);
        int nbase = nq * 16;
        #pragma unroll
        for (int i = 0; i < 16; ++i) tile[nbase + i][c_loc] = (bf16)vv[i];
    }
    __syncthreads();
    {
        int n_loc = t >> 2;
        int cq = t & 3;
        bf16* dst = xb + ((((size_t)b * 8 + kt) * NSP) + nb * 64 + n_loc) * 64 + cq * 16;
        *(uint4*)(dst)     = *(const uint4*)&tile[n_loc][cq * 16];
        *(uint4*)(dst + 8) = *(const uint4*)&tile[n_loc][cq * 16 + 8];
    }
}

// ---------------------------------------------------------------------------
// K1: fused projection GEMM. theta/phi -> [b][n][ci]; g -> TRANSPOSED [b][o][n]
// ---------------------------------------------------------------------------
__launch_bounds__(256, 2)
__global__ void proj_gemm(const bf16* __restrict__ xb, const bf16* __restrict__ wc,
                          const float* __restrict__ bt, const float* __restrict__ bp,
                          const float* __restrict__ bg,
                          bf16* __restrict__ theta, bf16* __restrict__ phi, bf16* __restrict__ gt) {
    constexpr int LDA = 72;
    __shared__ __align__(16) bf16 sm[2 * 128 * LDA];
    bf16* As = sm;
    bf16* Bs = sm + 128 * LDA;
    int b = blockIdx.z;
    int n0 = blockIdx.y * 128;
    int oc0 = blockIdx.x * 128;
    int t = threadIdx.x, lane = t & 63, wid = t >> 6;
    int wm = wid >> 1, wn = wid & 1;
    int l15 = lane & 15, quad = lane >> 4;

    f32x4 acc[4][4] = {};
    for (int kt = 0; kt < 8; ++kt) {
        __syncthreads();
        const bf16* asrc = xb + ((((size_t)b * 8 + kt) * NSP) + n0) * 64;
        const bf16* bsrc = wc + ((size_t)kt * OCH + oc0) * 64;
        for (int s = t; s < 1024; s += 256) {
            int row = s >> 3, c8 = s & 7;
            *(uint4*)&As[row * LDA + c8 * 8] = *(const uint4*)(asrc + (size_t)s * 8);
            *(uint4*)&Bs[row * LDA + c8 * 8] = *(const uint4*)(bsrc + (size_t)s * 8);
        }
        __syncthreads();
        #pragma unroll
        for (int kc = 0; kc < 2; ++kc) {
            bf16x8 af[4], bfv[4];
            #pragma unroll
            for (int i = 0; i < 4; ++i) {
                af[i]  = *(const bf16x8*)&As[(wm * 64 + i * 16 + l15) * LDA + kc * 32 + quad * 8];
                bfv[i] = *(const bf16x8*)&Bs[(wn * 64 + i * 16 + l15) * LDA + kc * 32 + quad * 8];
            }
            #pragma unroll
            for (int i = 0; i < 4; ++i)
                #pragma unroll
                for (int j = 0; j < 4; ++j)
                    acc[i][j] = __builtin_amdgcn_mfma_f32_16x16x32_bf16(af[i], bfv[j], acc[i][j], 0, 0, 0);
        }
    }
    if (oc0 < 512) {
        const float* bias; bf16* dst; int obase;
        if (oc0 < 256) { bias = bt; dst = theta; obase = oc0; }
        else           { bias = bp; dst = phi;   obase = oc0 - 256; }
        #pragma unroll
        for (int j = 0; j < 4; ++j) {
            int och = wn * 64 + j * 16 + l15;
            float bv = bias[obase + och];
            #pragma unroll
            for (int i = 0; i < 4; ++i) {
                int nrow = n0 + wm * 64 + i * 16 + quad * 4;
                bf16* p = dst + ((size_t)b * NSP + nrow) * CI + obase + och;
                #pragma unroll
                for (int r = 0; r < 4; ++r)
                    p[(size_t)r * CI] = (bf16)(acc[i][j][r] + bv);
            }
        }
    } else {
        // g : transpose tile in LDS, write [b][o][n] coalesced
        constexpr int LT = 136;
        int obase = oc0 - 512;
        __syncthreads();
        bf16* T = sm;
        #pragma unroll
        for (int j = 0; j < 4; ++j) {
            int och = wn * 64 + j * 16 + l15;
            float bv = bg[obase + och];
            #pragma unroll
            for (int i = 0; i < 4; ++i) {
                int nl = wm * 64 + i * 16 + quad * 4;
                bf16 tmp[4];
                #pragma unroll
                for (int r = 0; r < 4; ++r) tmp[r] = (bf16)(acc[i][j][r] + bv);
                *(uint2*)&T[och * LT + nl] = *(const uint2*)tmp;
            }
        }
        __syncthreads();
        for (int s = t; s < 2048; s += 256) {
            int row = s >> 4, part = s & 15;
            *(uint4*)(gt + ((size_t)b * CI + obase + row) * NSP + n0 + part * 8) =
                *(const uint4*)&T[row * LT + part * 8];
        }
    }
}

// ---------------------------------------------------------------------------
// K2: fused attention, single-pass online softmax.
// K single-buffered, V double-buffered, register prefetch a full phase ahead.
// XOR bank swizzle (no padding). LDS = 54272 B. Width-64 shuffles only.
// XCD swizzle: batch b -> XCD b%8 (phi/g L2 reuse).
// ---------------------------------------------------------------------------
__launch_bounds__(256, 2)
__global__ void attn_kernel(const bf16* __restrict__ theta, const bf16* __restrict__ phi,
                            const bf16* __restrict__ gt, bf16* __restrict__ y) {
    constexpr int LP = 40;
    __shared__ __align__(16) char smem[54272];
    bf16* Ks = (bf16*)smem;                       // [32 keys][256 ch] 16384 B
    bf16* Pw = (bf16*)(smem + 49152);             // [4][16][LP] 5120 B

    int id = blockIdx.x;
    int j = id >> 3;
    int qt = j & 15;
    int b = (id & 7) + 8 * (j >> 4);

    int t = threadIdx.x, lane = t & 63, w = t >> 6;
    int l15 = lane & 15, quad = lane >> 4;

    const bf16* th_b = theta + ((size_t)b * NSP + qt * 64) * CI;
    const bf16* ph_b = phi + (size_t)b * NSP * CI;
    const bf16* gt_b = gt + (size_t)b * CI * NSP;

    // Q fragments directly from global (one-time)
    bf16x8 qf[8];
    {
        const bf16* qrow = th_b + (size_t)(w * 16 + l15) * CI;
        #pragma unroll
        for (int kc = 0; kc < 8; ++kc)
            qf[kc] = *(const bf16x8*)(qrow + kc * 32 + quad * 8);
    }

    // stage K[0] and V[0]
    uint4 kreg[4], vreg[4];
    #pragma unroll
    for (int ss = 0; ss < 4; ++ss) {
        int G = t + ss * 256;
        kreg[ss] = *(const uint4*)(ph_b + (size_t)G * 8);
        vreg[ss] = *(const uint4*)(gt_b + (size_t)(G >> 2) * NSP + (G & 3) * 8);
    }
    {
        bf16* V0 = (bf16*)(smem + 16384);
        #pragma unroll
        for (int ss = 0; ss < 4; ++ss) {
            int G = t + ss * 256;
            int kr = G >> 5, kg = G & 31;
            *(uint4*)(Ks + kr * 256 + ((kg ^ (kr & 7)) << 3)) = kreg[ss];
            int vr = G >> 2, vg = G & 3;
            *(uint4*)(V0 + vr * 32 + ((vg ^ ((vr >> 1) & 3)) << 3)) = vreg[ss];
        }
    }
    __syncthreads();

    f32x4 oacc[16] = {};
    float m[4] = {-1e30f, -1e30f, -1e30f, -1e30f};
    float ps[4] = {0.f, 0.f, 0.f, 0.f};

    for (int kt = 0; kt < 32; ++kt) {
        bf16* Vc = (bf16*)(smem + 16384 + ((kt & 1) << 14));
        bf16* Vn = (bf16*)(smem + 16384 + (((kt + 1) & 1) << 14));
        // (a) issue global prefetch of K[kt+1], V[kt+1]
        if (kt < 31) {
            const bf16* ksrc = ph_b + (size_t)(kt + 1) * 32 * CI;
            const bf16* vsrc = gt_b + (kt + 1) * 32;
            #pragma unroll
            for (int ss = 0; ss < 4; ++ss) {
                int G = t + ss * 256;
                kreg[ss] = *(const uint4*)(ksrc + (size_t)G * 8);
                vreg[ss] = *(const uint4*)(vsrc + (size_t)(G >> 2) * NSP + (G & 3) * 8);
            }
        }
        // (b) QK^T from Ks
        f32x4 s0 = {}, s1 = {};
        #pragma unroll
        for (int kc = 0; kc < 8; ++kc) {
            int g0 = (kc * 4 + quad) ^ (l15 & 7);
            bf16x8 kf0 = *(const bf16x8*)(Ks + l15 * 256 + (g0 << 3));
            bf16x8 kf1 = *(const bf16x8*)(Ks + (16 + l15) * 256 + (g0 << 3));
            s0 = __builtin_amdgcn_mfma_f32_16x16x32_bf16(qf[kc], kf0, s0, 0, 0, 0);
            s1 = __builtin_amdgcn_mfma_f32_16x16x32_bf16(qf[kc], kf1, s1, 0, 0, 0);
        }
        __syncthreads();   // #1: all waves done reading Ks
        // (c) drain prefetch into LDS: K[kt+1] over Ks, V[kt+1] into Vn
        if (kt < 31) {
            #pragma unroll
            for (int ss = 0; ss < 4; ++ss) {
                int G = t + ss * 256;
                int kr = G >> 5, kg = G & 31;
                *(uint4*)(Ks + kr * 256 + ((kg ^ (kr & 7)) << 3)) = kreg[ss];
                int vr = G >> 2, vg = G & 3;
                *(uint4*)(Vn + vr * 32 + ((vg ^ ((vr >> 1) & 3)) << 3)) = vreg[ss];
            }
        }
        // (d) online softmax (width-64 shuffles; offsets<16 stay in-group)
        float cmx[4]; int flag = 0;
        #pragma unroll
        for (int r = 0; r < 4; ++r) {
            float c = fmaxf(s0[r], s1[r]);
            c = fmaxf(c, __shfl_xor(c, 1));
            c = fmaxf(c, __shfl_xor(c, 2));
            c = fmaxf(c, __shfl_xor(c, 4));
            c = fmaxf(c, __shfl_xor(c, 8));
            cmx[r] = c;
            flag |= (c > m[r]) ? 1 : 0;
        }
        if (__any(flag)) {
            float alpha[4];
            #pragma unroll
            for (int r = 0; r < 4; ++r) {
                float mn = fmaxf(m[r], cmx[r]);
                alpha[r] = __expf(m[r] - mn);
                m[r] = mn;
                ps[r] *= alpha[r];
            }
            #pragma unroll
            for (int nt = 0; nt < 16; ++nt) {
                oacc[nt][0] *= alpha[0];
                oacc[nt][1] *= alpha[1];
                oacc[nt][2] *= alpha[2];
                oacc[nt][3] *= alpha[3];
            }
        }
        #pragma unroll
        for (int r = 0; r < 4; ++r) {
            float p0 = __expf(s0[r] - m[r]);
            float p1 = __expf(s1[r] - m[r]);
            ps[r] += p0 + p1;
            Pw[(w * 16 + quad * 4 + r) * LP + l15]      = (bf16)p0;
            Pw[(w * 16 + quad * 4 + r) * LP + 16 + l15] = (bf16)p1;
        }
        // (e) PV from Vc (P roundtrip is wave-local)
        bf16x8 pf = *(const bf16x8*)&Pw[(w * 16 + l15) * LP + quad * 8];
        #pragma unroll
        for (int nt = 0; nt < 16; ++nt) {
            int vr = nt * 16 + l15;
            bf16x8 vf = *(const bf16x8*)(Vc + vr * 32 + ((quad ^ ((vr >> 1) & 3)) << 3));
            oacc[nt] = __builtin_amdgcn_mfma_f32_16x16x32_bf16(pf, vf, oacc[nt], 0, 0, 0);
        }
        __syncthreads();   // #2: Ks/Vn writes visible; Vc reads done
    }

    #pragma unroll
    for (int r = 0; r < 4; ++r) {
        ps[r] += __shfl_xor(ps[r], 1);
        ps[r] += __shfl_xor(ps[r], 2);
        ps[r] += __shfl_xor(ps[r], 4);
        ps[r] += __shfl_xor(ps[r], 8);
    }
    float inv[4];
    #pragma unroll
    for (int r = 0; r < 4; ++r) inv[r] = 1.0f / ps[r];

    int nrow = qt * 64 + w * 16 + quad * 4;
    #pragma unroll
    for (int nt = 0; nt < 16; ++nt) {
        int o = nt * 16 + l15;
        bf16* dst = y + ((((size_t)b * 4 + (o >> 6)) * NSP) + nrow) * 64 + (o & 63);
        #pragma unroll
        for (int r = 0; r < 4; ++r)
            dst[(size_t)r * 64] = (bf16)(oacc[nt][r] * inv[r]);
    }
}

// ---------------------------------------------------------------------------
// K3: output GEMM + fused BN stats (shuffle-reduce + atomicAdd). (R2-proven)
// ---------------------------------------------------------------------------
__launch_bounds__(256, 2)
__global__ void out_gemm(const bf16* __restrict__ y, const bf16* __restrict__ wz,
                         const float* __restrict__ bz, float* __restrict__ wy,
                         float* __restrict__ sums) {
    constexpr int LDA = 72;
    __shared__ __align__(16) bf16 As[128 * LDA];
    __shared__ __align__(16) bf16 Bs[128 * LDA];
    int b = blockIdx.z;
    int co0 = blockIdx.y * 128;
    int n0 = blockIdx.x * 128;
    int t = threadIdx.x, lane = t & 63, wid = t >> 6;
    int wm = wid >> 1, wn = wid & 1;
    int l15 = lane & 15, quad = lane >> 4;

    f32x4 acc[4][4] = {};
    for (int kt = 0; kt < 4; ++kt) {
        __syncthreads();
        const bf16* asrc = wz + ((size_t)kt * CH + co0) * 64;
        const bf16* bsrc = y + ((((size_t)b * 4 + kt) * NSP) + n0) * 64;
        for (int s = t; s < 1024; s += 256) {
            int row = s >> 3, c8 = s & 7;
            *(uint4*)&As[row * LDA + c8 * 8] = *(const uint4*)(asrc + (size_t)s * 8);
            *(uint4*)&Bs[row * LDA + c8 * 8] = *(const uint4*)(bsrc + (size_t)s * 8);
        }
        __syncthreads();
        #pragma unroll
        for (int kc = 0; kc < 2; ++kc) {
            bf16x8 af[4], bfv[4];
            #pragma unroll
            for (int i = 0; i < 4; ++i) {
                af[i]  = *(const bf16x8*)&As[(wm * 64 + i * 16 + l15) * LDA + kc * 32 + quad * 8];
                bfv[i] = *(const bf16x8*)&Bs[(wn * 64 + i * 16 + l15) * LDA + kc * 32 + quad * 8];
            }
            #pragma unroll
            for (int i = 0; i < 4; ++i)
                #pragma unroll
                for (int j = 0; j < 4; ++j)
                    acc[i][j] = __builtin_amdgcn_mfma_f32_16x16x32_bf16(af[i], bfv[j], acc[i][j], 0, 0, 0);
        }
    }
    #pragma unroll
    for (int i = 0; i < 4; ++i) {
        int cbase = co0 + wm * 64 + i * 16 + quad * 4;
        #pragma unroll
        for (int r = 0; r < 4; ++r) {
            int c = cbase + r;
            float bv = bz[c];
            float s = 0.f, s2 = 0.f;
            #pragma unroll
            for (int jj = 0; jj < 4; ++jj) {
                int n = n0 + wn * 64 + jj * 16 + l15;
                float v = acc[i][jj][r] + bv;
                wy[((size_t)b * CH + c) * NSP + n] = v;
                s += v; s2 += v * v;
            }
            s  += __shfl_xor(s, 1);  s2 += __shfl_xor(s2, 1);
            s  += __shfl_xor(s, 2);  s2 += __shfl_xor(s2, 2);
            s  += __shfl_xor(s, 4);  s2 += __shfl_xor(s2, 4);
            s  += __shfl_xor(s, 8);  s2 += __shfl_xor(s2, 8);
            if (l15 == 0) {
                atomicAdd(&sums[c], s);
                atomicAdd(&sums[CH + c], s2);
            }
        }
    }
}

// ---------------------------------------------------------------------------
// K4: BN normalize + affine + residual, in-place on d_out. float4.
// ---------------------------------------------------------------------------
__global__ void bn_finalize(float* __restrict__ out, const float* __restrict__ x,
                            const float* __restrict__ sums,
                            const float* __restrict__ gamma, const float* __restrict__ beta) {
    size_t idx4 = (size_t)blockIdx.x * 256 + threadIdx.x;
    size_t flat = idx4 * 4;
    int ch = (int)((flat >> 10) & 511);
    float S = sums[ch], S2 = sums[CH + ch];
    const float invcnt = 1.0f / (BATCH * NSP);
    float mean = S * invcnt;
    float var = S2 * invcnt - mean * mean;
    float sc = rsqrtf(var + EPSV) * gamma[ch];
    float bi = beta[ch] - mean * sc;
    float4 wv = *(float4*)(out + flat);
    float4 xv = *(const float4*)(x + flat);
    wv.x = wv.x * sc + bi + xv.x;
    wv.y = wv.y * sc + bi + xv.y;
    wv.z = wv.z * sc + bi + xv.z;
    wv.w = wv.w * sc + bi + xv.w;
    *(float4*)(out + flat) = wv;
}

// ---------------------------------------------------------------------------
extern "C" void kernel_launch(void* const* d_in, const int* in_sizes, int n_in,
                              void* d_out, int out_size, void* d_ws, size_t ws_size,
                              hipStream_t stream) {
    const float* x     = (const float*)d_in[0];
    const float* Wg    = (const float*)d_in[1];
    const float* bg    = (const float*)d_in[2];
    const float* Wt    = (const float*)d_in[3];
    const float* bt    = (const float*)d_in[4];
    const float* Wp    = (const float*)d_in[5];
    const float* bp    = (const float*)d_in[6];
    const float* Wz    = (const float*)d_in[7];
    const float* bz    = (const float*)d_in[8];
    const float* gamma = (const float*)d_in[9];
    const float* beta  = (const float*)d_in[10];
    float* out = (float*)d_out;

    char* ws = (char*)d_ws;
    bf16*  y_t   = (bf16*)(ws);                   // [32][4][1024][64]  16,777,216 B
    bf16*  g_t   = (bf16*)(ws + 16777216);        // [32][256][1024]   16,777,216 B
    bf16*  wc    = (bf16*)(ws + 33554432);        // [8][768][64]         786,432 B
    bf16*  wzb   = (bf16*)(ws + 34340864);        // [4][512][64]         262,144 B
    float* sums  = (float*)(ws + 34603008);       // [2][512]               4,096 B

    char* ob = (char*)d_out;                      // d_out as scratch until out_gemm
    bf16* xb    = (bf16*)(ob);                    // [32][8][1024][64] 33,554,432 B
    bf16* theta = (bf16*)(ob + 33554432);         // [32][1024][256]   16,777,216 B
    bf16* phi   = (bf16*)(ob + 50331648);         // [32][1024][256]   16,777,216 B

    prep_weights<<<dim3(2048), dim3(256), 0, stream>>>(Wg, Wt, Wp, Wz, wc, wzb);
    zero_sums<<<dim3(1), dim3(256), 0, stream>>>(sums);
    transpose_x<<<dim3(16, 8, 32), dim3(256), 0, stream>>>(x, xb);
    proj_gemm<<<dim3(6, 8, 32), dim3(256), 0, stream>>>(xb, wc, bt, bp, bg, theta, phi, g_t);
    attn_kernel<<<dim3(512), dim3(256), 0, stream>>>(theta, phi, g_t, y_t);
    out_gemm<<<dim3(8, 4, 32), dim3(256), 0, stream>>>(y_t, wzb, bz, out, sums);
    bn_finalize<<<dim3(16384), dim3(256), 0, stream>>>(out, x, sums, gamma, beta);
}

// Round 6
// 361.124 us; speedup vs baseline: 1.2917x; 1.2917x over previous
//
#include <hip/hip_runtime.h>
#include <math.h>

typedef __bf16 bf16;
typedef __bf16 bf16x8 __attribute__((ext_vector_type(8)));
typedef float f32x4 __attribute__((ext_vector_type(4)));
typedef unsigned short u16;
typedef unsigned int u32;

constexpr int BATCH = 32;
constexpr int CH    = 512;   // C
constexpr int CI    = 256;   // C/2
constexpr int NSP   = 1024;  // H*W
constexpr int OCH   = 768;   // 3*CI (theta|phi|g concat)
constexpr float EPSV = 1e-5f;

// async global->LDS, 16B per lane: LDS dest = wave-uniform base + lane*16
__device__ __forceinline__ void gload_lds16(const bf16* g, bf16* l) {
    __builtin_amdgcn_global_load_lds(
        (const __attribute__((address_space(1))) void*)g,
        (__attribute__((address_space(3))) void*)l, 16, 0, 0);
}

// ---------------------------------------------------------------------------
// K0a: weights -> bf16, k-blocked tiles of 64. Also zeroes the BN sums.
// ---------------------------------------------------------------------------
__global__ void prep_weights(const float* __restrict__ Wg, const float* __restrict__ Wt,
                             const float* __restrict__ Wp, const float* __restrict__ Wz,
                             bf16* __restrict__ wc, bf16* __restrict__ wz,
                             float* __restrict__ sums) {
    int tid = blockIdx.x * 256 + threadIdx.x;
    if (tid < 1024) sums[tid] = 0.0f;
    if (tid < OCH * CH) {
        int r = tid / CH, c = tid % CH;
        float v;
        if (r < 256)      v = Wt[r * CH + c];
        else if (r < 512) v = Wp[(r - 256) * CH + c];
        else              v = Wg[(r - 512) * CH + c];
        wc[(size_t)(c >> 6) * (OCH * 64) + r * 64 + (c & 63)] = (bf16)v;
    } else {
        int t2 = tid - OCH * CH;
        if (t2 < CH * CI) {
            int r = t2 / CI, o = t2 % CI;
            wz[(size_t)(o >> 6) * (CH * 64) + r * 64 + (o & 63)] = (bf16)Wz[r * CI + o];
        }
    }
}

// ---------------------------------------------------------------------------
// K0b: x [b][c][n] fp32 -> xb [b][kt][n][64] bf16 (64x64 LDS transpose tiles)
// ---------------------------------------------------------------------------
__global__ void transpose_x(const float* __restrict__ x, bf16* __restrict__ xb) {
    __shared__ bf16 tile[64][64];
    int b = blockIdx.z, kt = blockIdx.y, nb = blockIdx.x;
    int t = threadIdx.x;
    {
        int c_loc = t >> 2;
        int nq = t & 3;
        const float* src = x + ((size_t)b * CH + kt * 64 + c_loc) * NSP + nb * 64 + nq * 16;
        float vv[16];
        *(float4*)(vv + 0)  = *(const float4*)(src + 0);
        *(float4*)(vv + 4)  = *(const float4*)(src + 4);
        *(float4*)(vv + 8)  = *(const float4*)(src + 8);
        *(float4*)(vv + 12) = *(const float4*)(src + 12);
        int nbase = nq * 16;
        #pragma unroll
        for (int i = 0; i < 16; ++i) tile[nbase + i][c_loc] = (bf16)vv[i];
    }
    __syncthreads();
    {
        int n_loc = t >> 2;
        int cq = t & 3;
        bf16* dst = xb + ((((size_t)b * 8 + kt) * NSP) + nb * 64 + n_loc) * 64 + cq * 16;
        *(uint4*)(dst)     = *(const uint4*)&tile[n_loc][cq * 16];
        *(uint4*)(dst + 8) = *(const uint4*)&tile[n_loc][cq * 16 + 8];
    }
}

// ---------------------------------------------------------------------------
// K1: fused projection GEMM.
//   theta -> linear [b][n][ci] (Q read once, direct from global)
//   phi   -> BLOCKED K-tiles: [b][kt(32)] of 8192 bf16; within a tile,
//            element (n,c) at chunk ((h*8+kc)*64 + qd*16 + row16)*8 + e,
//            h=(n>>4)&1,row16=n&15,kc=c>>5,qd=(c>>3)&3,e=c&7.
//            Identity-copied to LDS -> fragment reads are lane-contiguous.
//   g     -> BLOCKED V-tiles: [b][kt(32)] of 8192 bf16; element (o,k) at
//            chunk ((o>>4)*64 + (k>>3)*16 + (o&15))*8 + (k&7).
// ---------------------------------------------------------------------------
__launch_bounds__(256, 2)
__global__ void proj_gemm(const bf16* __restrict__ xb, const bf16* __restrict__ wc,
                          const float* __restrict__ bt, const float* __restrict__ bp,
                          const float* __restrict__ bg,
                          bf16* __restrict__ theta, bf16* __restrict__ phi_t,
                          bf16* __restrict__ gt_t) {
    constexpr int LDA = 72;
    __shared__ __align__(16) bf16 sm[2 * 128 * LDA];
    bf16* As = sm;
    bf16* Bs = sm + 128 * LDA;
    int b = blockIdx.z;
    int n0 = blockIdx.y * 128;
    int oc0 = blockIdx.x * 128;
    int t = threadIdx.x, lane = t & 63, wid = t >> 6;
    int wm = wid >> 1, wn = wid & 1;
    int l15 = lane & 15, quad = lane >> 4;

    f32x4 acc[4][4] = {};
    for (int kt = 0; kt < 8; ++kt) {
        __syncthreads();
        const bf16* asrc = xb + ((((size_t)b * 8 + kt) * NSP) + n0) * 64;
        const bf16* bsrc = wc + ((size_t)kt * OCH + oc0) * 64;
        for (int s = t; s < 1024; s += 256) {
            int row = s >> 3, c8 = s & 7;
            *(uint4*)&As[row * LDA + c8 * 8] = *(const uint4*)(asrc + (size_t)s * 8);
            *(uint4*)&Bs[row * LDA + c8 * 8] = *(const uint4*)(bsrc + (size_t)s * 8);
        }
        __syncthreads();
        #pragma unroll
        for (int kc = 0; kc < 2; ++kc) {
            bf16x8 af[4], bfv[4];
            #pragma unroll
            for (int i = 0; i < 4; ++i) {
                af[i]  = *(const bf16x8*)&As[(wm * 64 + i * 16 + l15) * LDA + kc * 32 + quad * 8];
                bfv[i] = *(const bf16x8*)&Bs[(wn * 64 + i * 16 + l15) * LDA + kc * 32 + quad * 8];
            }
            #pragma unroll
            for (int i = 0; i < 4; ++i)
                #pragma unroll
                for (int j = 0; j < 4; ++j)
                    acc[i][j] = __builtin_amdgcn_mfma_f32_16x16x32_bf16(af[i], bfv[j], acc[i][j], 0, 0, 0);
        }
    }
    if (oc0 < 256) {
        // theta: linear [b][n][ci]
        #pragma unroll
        for (int j = 0; j < 4; ++j) {
            int och = oc0 + wn * 64 + j * 16 + l15;
            float bv = bt[och];
            #pragma unroll
            for (int i = 0; i < 4; ++i) {
                int nrow = n0 + wm * 64 + i * 16 + quad * 4;
                bf16* p = theta + ((size_t)b * NSP + nrow) * CI + och;
                #pragma unroll
                for (int r = 0; r < 4; ++r)
                    p[(size_t)r * CI] = (bf16)(acc[i][j][r] + bv);
            }
        }
    } else if (oc0 < 512) {
        // phi: blocked K-tiles
        bf16* dstb = phi_t + (size_t)b * 262144;
        #pragma unroll
        for (int j = 0; j < 4; ++j) {
            int och = (oc0 - 256) + wn * 64 + j * 16 + l15;
            float bv = bp[och];
            int kc = och >> 5, qd = (och >> 3) & 3, e = och & 7;
            #pragma unroll
            for (int i = 0; i < 4; ++i) {
                int nrow = n0 + wm * 64 + i * 16 + quad * 4;   // row16 base = quad*4
                int kt = nrow >> 5, h = (nrow >> 4) & 1;
                bf16* p = dstb + (size_t)kt * 8192 +
                          (size_t)(((h * 8 + kc) * 64 + qd * 16 + quad * 4) * 8) + e;
                #pragma unroll
                for (int r = 0; r < 4; ++r)
                    p[r * 8] = (bf16)(acc[i][j][r] + bv);
            }
        }
    } else {
        // g: transpose tile in LDS, then write blocked V-tiles (uint4 = 1 chunk)
        constexpr int LT = 136;
        int obase = oc0 - 512;
        __syncthreads();
        bf16* T = sm;
        #pragma unroll
        for (int j = 0; j < 4; ++j) {
            int och = wn * 64 + j * 16 + l15;
            float bv = bg[obase + och];
            #pragma unroll
            for (int i = 0; i < 4; ++i) {
                int nl = wm * 64 + i * 16 + quad * 4;
                bf16 tmp[4];
                #pragma unroll
                for (int r = 0; r < 4; ++r) tmp[r] = (bf16)(acc[i][j][r] + bv);
                *(uint2*)&T[och * LT + nl] = *(const uint2*)tmp;
            }
        }
        __syncthreads();
        bf16* dstb = gt_t + (size_t)b * 262144;
        for (int s = t; s < 2048; s += 256) {
            int row = s >> 4, part = s & 15;
            int o = obase + row;
            int kglob = n0 + part * 8;
            int kt = kglob >> 5, qd = (kglob >> 3) & 3;
            *(uint4*)(dstb + (size_t)kt * 8192 +
                      (size_t)(((o >> 4) * 64 + qd * 16 + (o & 15)) * 8)) =
                *(const uint4*)&T[row * LT + part * 8];
        }
    }
}

// ---------------------------------------------------------------------------
// K2: fused attention, single-pass online softmax.
// Staging via global_load_lds (no staging registers -> no spill). K single-
// buffered, V double-buffered; blocked tiles = identity copy, fragment reads
// lane-contiguous (conflict-free). LDS 54272 B -> 3 blocks/CU.
// XCD swizzle: batch b -> XCD b%8 (phi/g L2 reuse).
// ---------------------------------------------------------------------------
__launch_bounds__(256, 2)
__global__ void attn_kernel(const bf16* __restrict__ theta, const bf16* __restrict__ phi_t,
                            const bf16* __restrict__ gt_t, bf16* __restrict__ y) {
    constexpr int LP = 40;
    __shared__ __align__(16) char smem[54272];
    bf16* Ks = (bf16*)smem;                       // 16384 B: one blocked K tile
    bf16* Pw = (bf16*)(smem + 49152);             // [4][16][LP] 5120 B

    int id = blockIdx.x;
    int j = id >> 3;
    int qt = j & 15;
    int b = (id & 7) + 8 * (j >> 4);

    int t = threadIdx.x, lane = t & 63, w = t >> 6;
    int l15 = lane & 15, quad = lane >> 4;

    const bf16* ph_b = phi_t + (size_t)b * 262144;
    const bf16* gt_b = gt_t + (size_t)b * 262144;

    // Q fragments directly from global (one-time)
    bf16x8 qf[8];
    {
        const bf16* qrow = theta + ((size_t)b * NSP + qt * 64 + w * 16 + l15) * CI;
        #pragma unroll
        for (int kc = 0; kc < 8; ++kc)
            qf[kc] = *(const bf16x8*)(qrow + kc * 32 + quad * 8);
    }

    // preload tile 0 (K -> Ks, V -> V0) via async DMA
    {
        const bf16* ksrc = ph_b + w * 2048 + lane * 8;
        const bf16* vsrc = gt_b + w * 2048 + lane * 8;
        bf16* kdst = Ks + w * 2048;
        bf16* vdst = (bf16*)(smem + 16384) + w * 2048;
        #pragma unroll
        for (int i = 0; i < 4; ++i) {
            gload_lds16(ksrc + i * 512, kdst + i * 512);
            gload_lds16(vsrc + i * 512, vdst + i * 512);
        }
    }
    __syncthreads();

    f32x4 oacc[16] = {};
    float m[4] = {-1e30f, -1e30f, -1e30f, -1e30f};
    float ps[4] = {0.f, 0.f, 0.f, 0.f};

    for (int kt = 0; kt < 32; ++kt) {
        bf16* Vc = (bf16*)(smem + 16384 + ((kt & 1) << 14));
        // (a) QK^T from Ks (lane-contiguous chunks)
        f32x4 s0 = {}, s1 = {};
        #pragma unroll
        for (int kc = 0; kc < 8; ++kc) {
            bf16x8 kf0 = *(const bf16x8*)(Ks + kc * 512 + lane * 8);
            bf16x8 kf1 = *(const bf16x8*)(Ks + 4096 + kc * 512 + lane * 8);
            s0 = __builtin_amdgcn_mfma_f32_16x16x32_bf16(qf[kc], kf0, s0, 0, 0, 0);
            s1 = __builtin_amdgcn_mfma_f32_16x16x32_bf16(qf[kc], kf1, s1, 0, 0, 0);
        }
        __syncthreads();   // #1: all waves done reading Ks
        // (b) async-stage K[kt+1] over Ks, V[kt+1] into the other V buffer
        if (kt < 31) {
            const bf16* ksrc = ph_b + (size_t)(kt + 1) * 8192 + w * 2048 + lane * 8;
            const bf16* vsrc = gt_b + (size_t)(kt + 1) * 8192 + w * 2048 + lane * 8;
            bf16* kdst = Ks + w * 2048;
            bf16* vdst = (bf16*)(smem + 16384 + (((kt + 1) & 1) << 14)) + w * 2048;
            #pragma unroll
            for (int i = 0; i < 4; ++i) {
                gload_lds16(ksrc + i * 512, kdst + i * 512);
                gload_lds16(vsrc + i * 512, vdst + i * 512);
            }
        }
        // (c) online softmax (width-64 shuffles; offsets<16 stay in 16-groups)
        float cmx[4]; int flag = 0;
        #pragma unroll
        for (int r = 0; r < 4; ++r) {
            float c = fmaxf(s0[r], s1[r]);
            c = fmaxf(c, __shfl_xor(c, 1));
            c = fmaxf(c, __shfl_xor(c, 2));
            c = fmaxf(c, __shfl_xor(c, 4));
            c = fmaxf(c, __shfl_xor(c, 8));
            cmx[r] = c;
            flag |= (c > m[r]) ? 1 : 0;
        }
        if (__any(flag)) {
            float alpha[4];
            #pragma unroll
            for (int r = 0; r < 4; ++r) {
                float mn = fmaxf(m[r], cmx[r]);
                alpha[r] = __expf(m[r] - mn);
                m[r] = mn;
                ps[r] *= alpha[r];
            }
            #pragma unroll
            for (int nt = 0; nt < 16; ++nt) {
                oacc[nt][0] *= alpha[0];
                oacc[nt][1] *= alpha[1];
                oacc[nt][2] *= alpha[2];
                oacc[nt][3] *= alpha[3];
            }
        }
        #pragma unroll
        for (int r = 0; r < 4; ++r) {
            float p0 = __expf(s0[r] - m[r]);
            float p1 = __expf(s1[r] - m[r]);
            ps[r] += p0 + p1;
            Pw[(w * 16 + quad * 4 + r) * LP + l15]      = (bf16)p0;
            Pw[(w * 16 + quad * 4 + r) * LP + 16 + l15] = (bf16)p1;
        }
        // (d) PV from Vc (P roundtrip is wave-local)
        bf16x8 pf = *(const bf16x8*)&Pw[(w * 16 + l15) * LP + quad * 8];
        #pragma unroll
        for (int nt = 0; nt < 16; ++nt) {
            bf16x8 vf = *(const bf16x8*)(Vc + nt * 512 + lane * 8);
            oacc[nt] = __builtin_amdgcn_mfma_f32_16x16x32_bf16(pf, vf, oacc[nt], 0, 0, 0);
        }
        __syncthreads();   // #2: drains DMA (vmcnt) -> staged tiles visible
    }

    #pragma unroll
    for (int r = 0; r < 4; ++r) {
        ps[r] += __shfl_xor(ps[r], 1);
        ps[r] += __shfl_xor(ps[r], 2);
        ps[r] += __shfl_xor(ps[r], 4);
        ps[r] += __shfl_xor(ps[r], 8);
    }
    float inv[4];
    #pragma unroll
    for (int r = 0; r < 4; ++r) inv[r] = 1.0f / ps[r];

    int nrow = qt * 64 + w * 16 + quad * 4;
    #pragma unroll
    for (int nt = 0; nt < 16; ++nt) {
        int o = nt * 16 + l15;
        bf16* dst = y + ((((size_t)b * 4 + (o >> 6)) * NSP) + nrow) * 64 + (o & 63);
        #pragma unroll
        for (int r = 0; r < 4; ++r)
            dst[(size_t)r * 64] = (bf16)(oacc[nt][r] * inv[r]);
    }
}

// ---------------------------------------------------------------------------
// K3: output GEMM + fused BN stats (shuffle-reduce + atomicAdd).
// ---------------------------------------------------------------------------
__launch_bounds__(256, 2)
__global__ void out_gemm(const bf16* __restrict__ y, const bf16* __restrict__ wz,
                         const float* __restrict__ bz, float* __restrict__ wy,
                         float* __restrict__ sums) {
    constexpr int LDA = 72;
    __shared__ __align__(16) bf16 As[128 * LDA];
    __shared__ __align__(16) bf16 Bs[128 * LDA];
    int b = blockIdx.z;
    int co0 = blockIdx.y * 128;
    int n0 = blockIdx.x * 128;
    int t = threadIdx.x, lane = t & 63, wid = t >> 6;
    int wm = wid >> 1, wn = wid & 1;
    int l15 = lane & 15, quad = lane >> 4;

    f32x4 acc[4][4] = {};
    for (int kt = 0; kt < 4; ++kt) {
        __syncthreads();
        const bf16* asrc = wz + ((size_t)kt * CH + co0) * 64;
        const bf16* bsrc = y + ((((size_t)b * 4 + kt) * NSP) + n0) * 64;
        for (int s = t; s < 1024; s += 256) {
            int row = s >> 3, c8 = s & 7;
            *(uint4*)&As[row * LDA + c8 * 8] = *(const uint4*)(asrc + (size_t)s * 8);
            *(uint4*)&Bs[row * LDA + c8 * 8] = *(const uint4*)(bsrc + (size_t)s * 8);
        }
        __syncthreads();
        #pragma unroll
        for (int kc = 0; kc < 2; ++kc) {
            bf16x8 af[4], bfv[4];
            #pragma unroll
            for (int i = 0; i < 4; ++i) {
                af[i]  = *(const bf16x8*)&As[(wm * 64 + i * 16 + l15) * LDA + kc * 32 + quad * 8];
                bfv[i] = *(const bf16x8*)&Bs[(wn * 64 + i * 16 + l15) * LDA + kc * 32 + quad * 8];
            }
            #pragma unroll
            for (int i = 0; i < 4; ++i)
                #pragma unroll
                for (int j = 0; j < 4; ++j)
                    acc[i][j] = __builtin_amdgcn_mfma_f32_16x16x32_bf16(af[i], bfv[j], acc[i][j], 0, 0, 0);
        }
    }
    #pragma unroll
    for (int i = 0; i < 4; ++i) {
        int cbase = co0 + wm * 64 + i * 16 + quad * 4;
        #pragma unroll
        for (int r = 0; r < 4; ++r) {
            int c = cbase + r;
            float bv = bz[c];
            float s = 0.f, s2 = 0.f;
            #pragma unroll
            for (int jj = 0; jj < 4; ++jj) {
                int n = n0 + wn * 64 + jj * 16 + l15;
                float v = acc[i][jj][r] + bv;
                wy[((size_t)b * CH + c) * NSP + n] = v;
                s += v; s2 += v * v;
            }
            s  += __shfl_xor(s, 1);  s2 += __shfl_xor(s2, 1);
            s  += __shfl_xor(s, 2);  s2 += __shfl_xor(s2, 2);
            s  += __shfl_xor(s, 4);  s2 += __shfl_xor(s2, 4);
            s  += __shfl_xor(s, 8);  s2 += __shfl_xor(s2, 8);
            if (l15 == 0) {
                atomicAdd(&sums[c], s);
                atomicAdd(&sums[CH + c], s2);
            }
        }
    }
}

// ---------------------------------------------------------------------------
// K4: BN normalize + affine + residual, in-place on d_out. float4.
// ---------------------------------------------------------------------------
__global__ void bn_finalize(float* __restrict__ out, const float* __restrict__ x,
                            const float* __restrict__ sums,
                            const float* __restrict__ gamma, const float* __restrict__ beta) {
    size_t idx4 = (size_t)blockIdx.x * 256 + threadIdx.x;
    size_t flat = idx4 * 4;
    int ch = (int)((flat >> 10) & 511);
    float S = sums[ch], S2 = sums[CH + ch];
    const float invcnt = 1.0f / (BATCH * NSP);
    float mean = S * invcnt;
    float var = S2 * invcnt - mean * mean;
    float sc = rsqrtf(var + EPSV) * gamma[ch];
    float bi = beta[ch] - mean * sc;
    float4 wv = *(float4*)(out + flat);
    float4 xv = *(const float4*)(x + flat);
    wv.x = wv.x * sc + bi + xv.x;
    wv.y = wv.y * sc + bi + xv.y;
    wv.z = wv.z * sc + bi + xv.z;
    wv.w = wv.w * sc + bi + xv.w;
    *(float4*)(out + flat) = wv;
}

// ---------------------------------------------------------------------------
extern "C" void kernel_launch(void* const* d_in, const int* in_sizes, int n_in,
                              void* d_out, int out_size, void* d_ws, size_t ws_size,
                              hipStream_t stream) {
    const float* x     = (const float*)d_in[0];
    const float* Wg    = (const float*)d_in[1];
    const float* bg    = (const float*)d_in[2];
    const float* Wt    = (const float*)d_in[3];
    const float* bt    = (const float*)d_in[4];
    const float* Wp    = (const float*)d_in[5];
    const float* bp    = (const float*)d_in[6];
    const float* Wz    = (const float*)d_in[7];
    const float* bz    = (const float*)d_in[8];
    const float* gamma = (const float*)d_in[9];
    const float* beta  = (const float*)d_in[10];
    float* out = (float*)d_out;

    char* ws = (char*)d_ws;
    bf16*  y_t   = (bf16*)(ws);                   // [32][4][1024][64]  16,777,216 B
    bf16*  g_t   = (bf16*)(ws + 16777216);        // blocked V tiles   16,777,216 B
    bf16*  wc    = (bf16*)(ws + 33554432);        // [8][768][64]         786,432 B
    bf16*  wzb   = (bf16*)(ws + 34340864);        // [4][512][64]         262,144 B
    float* sums  = (float*)(ws + 34603008);       // [2][512]               4,096 B

    char* ob = (char*)d_out;                      // d_out as scratch until out_gemm
    bf16* xb    = (bf16*)(ob);                    // [32][8][1024][64] 33,554,432 B
    bf16* theta = (bf16*)(ob + 33554432);         // [32][1024][256]   16,777,216 B
    bf16* phi_t = (bf16*)(ob + 50331648);         // blocked K tiles   16,777,216 B

    prep_weights<<<dim3(2048), dim3(256), 0, stream>>>(Wg, Wt, Wp, Wz, wc, wzb, sums);
    transpose_x<<<dim3(16, 8, 32), dim3(256), 0, stream>>>(x, xb);
    proj_gemm<<<dim3(6, 8, 32), dim3(256), 0, stream>>>(xb, wc, bt, bp, bg, theta, phi_t, g_t);
    attn_kernel<<<dim3(512), dim3(256), 0, stream>>>(theta, phi_t, g_t, y_t);
    out_gemm<<<dim3(8, 4, 32), dim3(256), 0, stream>>>(y_t, wzb, bz, out, sums);
    bn_finalize<<<dim3(16384), dim3(256), 0, stream>>>(out, x, sums, gamma, beta);
}

// Round 7
// 309.717 us; speedup vs baseline: 1.5061x; 1.1660x over previous
//
#include <hip/hip_runtime.h>
#include <math.h>

typedef __bf16 bf16;
typedef __bf16 bf16x8 __attribute__((ext_vector_type(8)));
typedef float f32x4 __attribute__((ext_vector_type(4)));
typedef unsigned short u16;
typedef unsigned int u32;

constexpr int BATCH = 32;
constexpr int CH    = 512;   // C
constexpr int CI    = 256;   // C/2
constexpr int NSP   = 1024;  // H*W
constexpr int OCH   = 768;   // 3*CI (theta|phi|g concat)
constexpr float EPSV = 1e-5f;

// async global->LDS, 16B per lane: LDS dest = wave-uniform base + lane*16
__device__ __forceinline__ void gload_lds16(const bf16* g, bf16* l) {
    __builtin_amdgcn_global_load_lds(
        (const __attribute__((address_space(1))) void*)g,
        (__attribute__((address_space(3))) void*)l, 16, 0, 0);
}

// ---------------------------------------------------------------------------
// K0a: weights -> bf16, k-blocked tiles of 64. Also zeroes the BN sums.
// ---------------------------------------------------------------------------
__global__ void prep_weights(const float* __restrict__ Wg, const float* __restrict__ Wt,
                             const float* __restrict__ Wp, const float* __restrict__ Wz,
                             bf16* __restrict__ wc, bf16* __restrict__ wz,
                             float* __restrict__ sums) {
    int tid = blockIdx.x * 256 + threadIdx.x;
    if (tid < 1024) sums[tid] = 0.0f;
    if (tid < OCH * CH) {
        int r = tid / CH, c = tid % CH;
        float v;
        if (r < 256)      v = Wt[r * CH + c];
        else if (r < 512) v = Wp[(r - 256) * CH + c];
        else              v = Wg[(r - 512) * CH + c];
        wc[(size_t)(c >> 6) * (OCH * 64) + r * 64 + (c & 63)] = (bf16)v;
    } else {
        int t2 = tid - OCH * CH;
        if (t2 < CH * CI) {
            int r = t2 / CI, o = t2 % CI;
            wz[(size_t)(o >> 6) * (CH * 64) + r * 64 + (o & 63)] = (bf16)Wz[r * CI + o];
        }
    }
}

// ---------------------------------------------------------------------------
// K0b: x [b][c][n] fp32 -> xb [b][kt][n][64] bf16 (64x64 LDS transpose tiles)
// ---------------------------------------------------------------------------
__global__ void transpose_x(const float* __restrict__ x, bf16* __restrict__ xb) {
    __shared__ bf16 tile[64][64];
    int b = blockIdx.z, kt = blockIdx.y, nb = blockIdx.x;
    int t = threadIdx.x;
    {
        int c_loc = t >> 2;
        int nq = t & 3;
        const float* src = x + ((size_t)b * CH + kt * 64 + c_loc) * NSP + nb * 64 + nq * 16;
        float vv[16];
        *(float4*)(vv + 0)  = *(const float4*)(src + 0);
        *(float4*)(vv + 4)  = *(const float4*)(src + 4);
        *(float4*)(vv + 8)  = *(const float4*)(src + 8);
        *(float4*)(vv + 12) = *(const float4*)(src + 12);
        int nbase = nq * 16;
        #pragma unroll
        for (int i = 0; i < 16; ++i) tile[nbase + i][c_loc] = (bf16)vv[i];
    }
    __syncthreads();
    {
        int n_loc = t >> 2;
        int cq = t & 3;
        bf16* dst = xb + ((((size_t)b * 8 + kt) * NSP) + nb * 64 + n_loc) * 64 + cq * 16;
        *(uint4*)(dst)     = *(const uint4*)&tile[n_loc][cq * 16];
        *(uint4*)(dst + 8) = *(const uint4*)&tile[n_loc][cq * 16 + 8];
    }
}

// ---------------------------------------------------------------------------
// K1: fused projection GEMM.
//   theta -> linear [b][n][ci]; phi/g -> BLOCKED MFMA-fragment tiles
//   (identity copy to LDS => lane-contiguous fragment reads in attention).
// ---------------------------------------------------------------------------
__launch_bounds__(256, 2)
__global__ void proj_gemm(const bf16* __restrict__ xb, const bf16* __restrict__ wc,
                          const float* __restrict__ bt, const float* __restrict__ bp,
                          const float* __restrict__ bg,
                          bf16* __restrict__ theta, bf16* __restrict__ phi_t,
                          bf16* __restrict__ gt_t) {
    constexpr int LDA = 72;
    __shared__ __align__(16) bf16 sm[2 * 128 * LDA];
    bf16* As = sm;
    bf16* Bs = sm + 128 * LDA;
    int b = blockIdx.z;
    int n0 = blockIdx.y * 128;
    int oc0 = blockIdx.x * 128;
    int t = threadIdx.x, lane = t & 63, wid = t >> 6;
    int wm = wid >> 1, wn = wid & 1;
    int l15 = lane & 15, quad = lane >> 4;

    f32x4 acc[4][4] = {};
    for (int kt = 0; kt < 8; ++kt) {
        __syncthreads();
        const bf16* asrc = xb + ((((size_t)b * 8 + kt) * NSP) + n0) * 64;
        const bf16* bsrc = wc + ((size_t)kt * OCH + oc0) * 64;
        for (int s = t; s < 1024; s += 256) {
            int row = s >> 3, c8 = s & 7;
            *(uint4*)&As[row * LDA + c8 * 8] = *(const uint4*)(asrc + (size_t)s * 8);
            *(uint4*)&Bs[row * LDA + c8 * 8] = *(const uint4*)(bsrc + (size_t)s * 8);
        }
        __syncthreads();
        #pragma unroll
        for (int kc = 0; kc < 2; ++kc) {
            bf16x8 af[4], bfv[4];
            #pragma unroll
            for (int i = 0; i < 4; ++i) {
                af[i]  = *(const bf16x8*)&As[(wm * 64 + i * 16 + l15) * LDA + kc * 32 + quad * 8];
                bfv[i] = *(const bf16x8*)&Bs[(wn * 64 + i * 16 + l15) * LDA + kc * 32 + quad * 8];
            }
            #pragma unroll
            for (int i = 0; i < 4; ++i)
                #pragma unroll
                for (int j = 0; j < 4; ++j)
                    acc[i][j] = __builtin_amdgcn_mfma_f32_16x16x32_bf16(af[i], bfv[j], acc[i][j], 0, 0, 0);
        }
    }
    if (oc0 < 256) {
        // theta: linear [b][n][ci]
        #pragma unroll
        for (int j = 0; j < 4; ++j) {
            int och = oc0 + wn * 64 + j * 16 + l15;
            float bv = bt[och];
            #pragma unroll
            for (int i = 0; i < 4; ++i) {
                int nrow = n0 + wm * 64 + i * 16 + quad * 4;
                bf16* p = theta + ((size_t)b * NSP + nrow) * CI + och;
                #pragma unroll
                for (int r = 0; r < 4; ++r)
                    p[(size_t)r * CI] = (bf16)(acc[i][j][r] + bv);
            }
        }
    } else if (oc0 < 512) {
        // phi: blocked K-tiles
        bf16* dstb = phi_t + (size_t)b * 262144;
        #pragma unroll
        for (int j = 0; j < 4; ++j) {
            int och = (oc0 - 256) + wn * 64 + j * 16 + l15;
            float bv = bp[och];
            int kc = och >> 5, qd = (och >> 3) & 3, e = och & 7;
            #pragma unroll
            for (int i = 0; i < 4; ++i) {
                int nrow = n0 + wm * 64 + i * 16 + quad * 4;   // row16 base = quad*4
                int kt = nrow >> 5, h = (nrow >> 4) & 1;
                bf16* p = dstb + (size_t)kt * 8192 +
                          (size_t)(((h * 8 + kc) * 64 + qd * 16 + quad * 4) * 8) + e;
                #pragma unroll
                for (int r = 0; r < 4; ++r)
                    p[r * 8] = (bf16)(acc[i][j][r] + bv);
            }
        }
    } else {
        // g: transpose tile in LDS, then write blocked V-tiles (uint4 = 1 chunk)
        constexpr int LT = 136;
        int obase = oc0 - 512;
        __syncthreads();
        bf16* T = sm;
        #pragma unroll
        for (int j = 0; j < 4; ++j) {
            int och = wn * 64 + j * 16 + l15;
            float bv = bg[obase + och];
            #pragma unroll
            for (int i = 0; i < 4; ++i) {
                int nl = wm * 64 + i * 16 + quad * 4;
                bf16 tmp[4];
                #pragma unroll
                for (int r = 0; r < 4; ++r) tmp[r] = (bf16)(acc[i][j][r] + bv);
                *(uint2*)&T[och * LT + nl] = *(const uint2*)tmp;
            }
        }
        __syncthreads();
        bf16* dstb = gt_t + (size_t)b * 262144;
        for (int s = t; s < 2048; s += 256) {
            int row = s >> 4, part = s & 15;
            int o = obase + row;
            int kglob = n0 + part * 8;
            int kt = kglob >> 5, qd = (kglob >> 3) & 3;
            *(uint4*)(dstb + (size_t)kt * 8192 +
                      (size_t)(((o >> 4) * 64 + qd * 16 + (o & 15)) * 8)) =
                *(const uint4*)&T[row * LT + part * 8];
        }
    }
}

// ---------------------------------------------------------------------------
// K2: fused attention, single-pass online softmax.
// DMA staging (no staging regs), K single-buffered, V double-buffered,
// blocked tiles -> lane-contiguous conflict-free fragment reads.
// LDS 54272 B x 3 = 162816 <= 163840 -> 3 blocks/CU (launch_bounds 3).
// XCD swizzle: batch b -> XCD b%8.
// ---------------------------------------------------------------------------
__launch_bounds__(256, 3)
__global__ void attn_kernel(const bf16* __restrict__ theta, const bf16* __restrict__ phi_t,
                            const bf16* __restrict__ gt_t, bf16* __restrict__ y) {
    constexpr int LP = 40;
    __shared__ __align__(16) char smem[54272];
    bf16* Ks = (bf16*)smem;                       // 16384 B: one blocked K tile
    bf16* Pw = (bf16*)(smem + 49152);             // [4][16][LP] 5120 B

    int id = blockIdx.x;
    int j = id >> 3;
    int qt = j & 15;
    int b = (id & 7) + 8 * (j >> 4);

    int t = threadIdx.x, lane = t & 63, w = t >> 6;
    int l15 = lane & 15, quad = lane >> 4;

    const bf16* ph_b = phi_t + (size_t)b * 262144;
    const bf16* gt_b = gt_t + (size_t)b * 262144;

    // Q fragments directly from global (one-time)
    bf16x8 qf[8];
    {
        const bf16* qrow = theta + ((size_t)b * NSP + qt * 64 + w * 16 + l15) * CI;
        #pragma unroll
        for (int kc = 0; kc < 8; ++kc)
            qf[kc] = *(const bf16x8*)(qrow + kc * 32 + quad * 8);
    }

    // preload tile 0 (K -> Ks, V -> V0) via async DMA
    {
        const bf16* ksrc = ph_b + w * 2048 + lane * 8;
        const bf16* vsrc = gt_b + w * 2048 + lane * 8;
        bf16* kdst = Ks + w * 2048;
        bf16* vdst = (bf16*)(smem + 16384) + w * 2048;
        #pragma unroll
        for (int i = 0; i < 4; ++i) {
            gload_lds16(ksrc + i * 512, kdst + i * 512);
            gload_lds16(vsrc + i * 512, vdst + i * 512);
        }
    }
    __syncthreads();

    f32x4 oacc[16] = {};
    float m[4] = {-1e30f, -1e30f, -1e30f, -1e30f};
    float ps[4] = {0.f, 0.f, 0.f, 0.f};

    for (int kt = 0; kt < 32; ++kt) {
        bf16* Vc = (bf16*)(smem + 16384 + ((kt & 1) << 14));
        // (a) QK^T from Ks (lane-contiguous chunks)
        f32x4 s0 = {}, s1 = {};
        #pragma unroll
        for (int kc = 0; kc < 8; ++kc) {
            bf16x8 kf0 = *(const bf16x8*)(Ks + kc * 512 + lane * 8);
            bf16x8 kf1 = *(const bf16x8*)(Ks + 4096 + kc * 512 + lane * 8);
            s0 = __builtin_amdgcn_mfma_f32_16x16x32_bf16(qf[kc], kf0, s0, 0, 0, 0);
            s1 = __builtin_amdgcn_mfma_f32_16x16x32_bf16(qf[kc], kf1, s1, 0, 0, 0);
        }
        __syncthreads();   // #1: all waves done reading Ks
        // (b) async-stage K[kt+1] over Ks, V[kt+1] into the other V buffer
        if (kt < 31) {
            const bf16* ksrc = ph_b + (size_t)(kt + 1) * 8192 + w * 2048 + lane * 8;
            const bf16* vsrc = gt_b + (size_t)(kt + 1) * 8192 + w * 2048 + lane * 8;
            bf16* kdst = Ks + w * 2048;
            bf16* vdst = (bf16*)(smem + 16384 + (((kt + 1) & 1) << 14)) + w * 2048;
            #pragma unroll
            for (int i = 0; i < 4; ++i) {
                gload_lds16(ksrc + i * 512, kdst + i * 512);
                gload_lds16(vsrc + i * 512, vdst + i * 512);
            }
        }
        // (c) online softmax (width-64 shuffles; offsets<16 stay in 16-groups)
        float cmx[4]; int flag = 0;
        #pragma unroll
        for (int r = 0; r < 4; ++r) {
            float c = fmaxf(s0[r], s1[r]);
            c = fmaxf(c, __shfl_xor(c, 1));
            c = fmaxf(c, __shfl_xor(c, 2));
            c = fmaxf(c, __shfl_xor(c, 4));
            c = fmaxf(c, __shfl_xor(c, 8));
            cmx[r] = c;
            flag |= (c > m[r]) ? 1 : 0;
        }
        if (__any(flag)) {
            float alpha[4];
            #pragma unroll
            for (int r = 0; r < 4; ++r) {
                float mn = fmaxf(m[r], cmx[r]);
                alpha[r] = __expf(m[r] - mn);
                m[r] = mn;
                ps[r] *= alpha[r];
            }
            #pragma unroll
            for (int nt = 0; nt < 16; ++nt) {
                oacc[nt][0] *= alpha[0];
                oacc[nt][1] *= alpha[1];
                oacc[nt][2] *= alpha[2];
                oacc[nt][3] *= alpha[3];
            }
        }
        #pragma unroll
        for (int r = 0; r < 4; ++r) {
            float p0 = __expf(s0[r] - m[r]);
            float p1 = __expf(s1[r] - m[r]);
            ps[r] += p0 + p1;
            Pw[(w * 16 + quad * 4 + r) * LP + l15]      = (bf16)p0;
            Pw[(w * 16 + quad * 4 + r) * LP + 16 + l15] = (bf16)p1;
        }
        // (d) PV from Vc (P roundtrip is wave-local)
        bf16x8 pf = *(const bf16x8*)&Pw[(w * 16 + l15) * LP + quad * 8];
        #pragma unroll
        for (int nt = 0; nt < 16; ++nt) {
            bf16x8 vf = *(const bf16x8*)(Vc + nt * 512 + lane * 8);
            oacc[nt] = __builtin_amdgcn_mfma_f32_16x16x32_bf16(pf, vf, oacc[nt], 0, 0, 0);
        }
        __syncthreads();   // #2: drains DMA (vmcnt) -> staged tiles visible
    }

    #pragma unroll
    for (int r = 0; r < 4; ++r) {
        ps[r] += __shfl_xor(ps[r], 1);
        ps[r] += __shfl_xor(ps[r], 2);
        ps[r] += __shfl_xor(ps[r], 4);
        ps[r] += __shfl_xor(ps[r], 8);
    }
    float inv[4];
    #pragma unroll
    for (int r = 0; r < 4; ++r) inv[r] = 1.0f / ps[r];

    int nrow = qt * 64 + w * 16 + quad * 4;
    #pragma unroll
    for (int nt = 0; nt < 16; ++nt) {
        int o = nt * 16 + l15;
        bf16* dst = y + ((((size_t)b * 4 + (o >> 6)) * NSP) + nrow) * 64 + (o & 63);
        #pragma unroll
        for (int r = 0; r < 4; ++r)
            dst[(size_t)r * 64] = (bf16)(oacc[nt][r] * inv[r]);
    }
}

// ---------------------------------------------------------------------------
// K3: output GEMM + fused BN stats. LDS cross-wave combine -> 128 atomic
// pairs per block. 4 blocks/CU (LDS 38.9 KB, VGPR 72).
// ---------------------------------------------------------------------------
__launch_bounds__(256, 4)
__global__ void out_gemm(const bf16* __restrict__ y, const bf16* __restrict__ wz,
                         const float* __restrict__ bz, float* __restrict__ wy,
                         float* __restrict__ sums) {
    constexpr int LDA = 72;
    __shared__ __align__(16) bf16 As[128 * LDA];
    __shared__ __align__(16) bf16 Bs[128 * LDA];
    __shared__ float redS[128][2], redS2[128][2];
    int b = blockIdx.z;
    int co0 = blockIdx.y * 128;
    int n0 = blockIdx.x * 128;
    int t = threadIdx.x, lane = t & 63, wid = t >> 6;
    int wm = wid >> 1, wn = wid & 1;
    int l15 = lane & 15, quad = lane >> 4;

    f32x4 acc[4][4] = {};
    for (int kt = 0; kt < 4; ++kt) {
        __syncthreads();
        const bf16* asrc = wz + ((size_t)kt * CH + co0) * 64;
        const bf16* bsrc = y + ((((size_t)b * 4 + kt) * NSP) + n0) * 64;
        for (int s = t; s < 1024; s += 256) {
            int row = s >> 3, c8 = s & 7;
            *(uint4*)&As[row * LDA + c8 * 8] = *(const uint4*)(asrc + (size_t)s * 8);
            *(uint4*)&Bs[row * LDA + c8 * 8] = *(const uint4*)(bsrc + (size_t)s * 8);
        }
        __syncthreads();
        #pragma unroll
        for (int kc = 0; kc < 2; ++kc) {
            bf16x8 af[4], bfv[4];
            #pragma unroll
            for (int i = 0; i < 4; ++i) {
                af[i]  = *(const bf16x8*)&As[(wm * 64 + i * 16 + l15) * LDA + kc * 32 + quad * 8];
                bfv[i] = *(const bf16x8*)&Bs[(wn * 64 + i * 16 + l15) * LDA + kc * 32 + quad * 8];
            }
            #pragma unroll
            for (int i = 0; i < 4; ++i)
                #pragma unroll
                for (int j = 0; j < 4; ++j)
                    acc[i][j] = __builtin_amdgcn_mfma_f32_16x16x32_bf16(af[i], bfv[j], acc[i][j], 0, 0, 0);
        }
    }
    #pragma unroll
    for (int i = 0; i < 4; ++i) {
        int cbase = co0 + wm * 64 + i * 16 + quad * 4;
        #pragma unroll
        for (int r = 0; r < 4; ++r) {
            int c = cbase + r;
            float bv = bz[c];
            float s = 0.f, s2 = 0.f;
            #pragma unroll
            for (int jj = 0; jj < 4; ++jj) {
                int n = n0 + wn * 64 + jj * 16 + l15;
                float v = acc[i][jj][r] + bv;
                wy[((size_t)b * CH + c) * NSP + n] = v;
                s += v; s2 += v * v;
            }
            s  += __shfl_xor(s, 1);  s2 += __shfl_xor(s2, 1);
            s  += __shfl_xor(s, 2);  s2 += __shfl_xor(s2, 2);
            s  += __shfl_xor(s, 4);  s2 += __shfl_xor(s2, 4);
            s  += __shfl_xor(s, 8);  s2 += __shfl_xor(s2, 8);
            if (l15 == 0) {
                int cl = wm * 64 + i * 16 + quad * 4 + r;
                redS[cl][wn]  = s;
                redS2[cl][wn] = s2;
            }
        }
    }
    __syncthreads();
    if (t < 128) {
        atomicAdd(&sums[co0 + t],      redS[t][0] + redS[t][1]);
        atomicAdd(&sums[CH + co0 + t], redS2[t][0] + redS2[t][1]);
    }
}

// ---------------------------------------------------------------------------
// K4: BN normalize + affine + residual, in-place on d_out. float4.
// ---------------------------------------------------------------------------
__global__ void bn_finalize(float* __restrict__ out, const float* __restrict__ x,
                            const float* __restrict__ sums,
                            const float* __restrict__ gamma, const float* __restrict__ beta) {
    size_t idx4 = (size_t)blockIdx.x * 256 + threadIdx.x;
    size_t flat = idx4 * 4;
    int ch = (int)((flat >> 10) & 511);
    float S = sums[ch], S2 = sums[CH + ch];
    const float invcnt = 1.0f / (BATCH * NSP);
    float mean = S * invcnt;
    float var = S2 * invcnt - mean * mean;
    float sc = rsqrtf(var + EPSV) * gamma[ch];
    float bi = beta[ch] - mean * sc;
    float4 wv = *(float4*)(out + flat);
    float4 xv = *(const float4*)(x + flat);
    wv.x = wv.x * sc + bi + xv.x;
    wv.y = wv.y * sc + bi + xv.y;
    wv.z = wv.z * sc + bi + xv.z;
    wv.w = wv.w * sc + bi + xv.w;
    *(float4*)(out + flat) = wv;
}

// ---------------------------------------------------------------------------
extern "C" void kernel_launch(void* const* d_in, const int* in_sizes, int n_in,
                              void* d_out, int out_size, void* d_ws, size_t ws_size,
                              hipStream_t stream) {
    const float* x     = (const float*)d_in[0];
    const float* Wg    = (const float*)d_in[1];
    const float* bg    = (const float*)d_in[2];
    const float* Wt    = (const float*)d_in[3];
    const float* bt    = (const float*)d_in[4];
    const float* Wp    = (const float*)d_in[5];
    const float* bp    = (const float*)d_in[6];
    const float* Wz    = (const float*)d_in[7];
    const float* bz    = (const float*)d_in[8];
    const float* gamma = (const float*)d_in[9];
    const float* beta  = (const float*)d_in[10];
    float* out = (float*)d_out;

    char* ws = (char*)d_ws;
    bf16*  y_t   = (bf16*)(ws);                   // [32][4][1024][64]  16,777,216 B
    bf16*  g_t   = (bf16*)(ws + 16777216);        // blocked V tiles   16,777,216 B
    bf16*  wc    = (bf16*)(ws + 33554432);        // [8][768][64]         786,432 B
    bf16*  wzb   = (bf16*)(ws + 34340864);        // [4][512][64]         262,144 B
    float* sums  = (float*)(ws + 34603008);       // [2][512]               4,096 B

    char* ob = (char*)d_out;                      // d_out as scratch until out_gemm
    bf16* xb    = (bf16*)(ob);                    // [32][8][1024][64] 33,554,432 B
    bf16* theta = (bf16*)(ob + 33554432);         // [32][1024][256]   16,777,216 B
    bf16* phi_t = (bf16*)(ob + 50331648);         // blocked K tiles   16,777,216 B

    prep_weights<<<dim3(2048), dim3(256), 0, stream>>>(Wg, Wt, Wp, Wz, wc, wzb, sums);
    transpose_x<<<dim3(16, 8, 32), dim3(256), 0, stream>>>(x, xb);
    proj_gemm<<<dim3(6, 8, 32), dim3(256), 0, stream>>>(xb, wc, bt, bp, bg, theta, phi_t, g_t);
    attn_kernel<<<dim3(512), dim3(256), 0, stream>>>(theta, phi_t, g_t, y_t);
    out_gemm<<<dim3(8, 4, 32), dim3(256), 0, stream>>>(y_t, wzb, bz, out, sums);
    bn_finalize<<<dim3(16384), dim3(256), 0, stream>>>(out, x, sums, gamma, beta);
}